// Round 1
// 292.917 us; speedup vs baseline: 1.0448x; 1.0448x over previous
//
#include <hip/hip_runtime.h>

// MADE flow: u = (x - m)*exp(-a), logdet = -sum(a)
// B=524288, NI=32, H=128, NC=64.
// R3: K=32 MFMA (16x16x32_f16) everywhere -> half the MFMA instrs and half
// the weight-load instrs vs K=16. Split-jt accumulator reuse cuts acc AGPRs
// 64->32 (total regs ~110 -> 4 waves/SIMD). Block 512 (8 waves) amortizes the
// 48KB LDS stage -> occupancy 12 -> 16 waves/CU. Staging via
// global_load_lds (no VGPR round-trip); barrier after L1 drains it.

#define B_ROWS 524288
#define NI 32
#define HD 128
#define NC 64

// K=32 fragments: 1 frag = 16(j) x 32(k) f16 = 512 halfs = 1KB
#define L2_BASE 24    // L1 frags: 8 jt * 3 kt = 24
#define L3_BASE 56    // L2 frags: 8 jt * 4 kt = 32
#define N_FRAGS 72    // L3 frags: 4 jt * 4 kt = 16

typedef _Float16 half8 __attribute__((ext_vector_type(8)));
typedef float f32x4 __attribute__((ext_vector_type(4)));

__device__ inline f32x4 relu4(f32x4 v) {
  v[0] = fmaxf(v[0], 0.f); v[1] = fmaxf(v[1], 0.f);
  v[2] = fmaxf(v[2], 0.f); v[3] = fmaxf(v[3], 0.f);
  return v;
}

__device__ inline half8 cvt8(f32x4 lo, f32x4 hi) {
  half8 h;
  h[0] = (_Float16)lo[0]; h[1] = (_Float16)lo[1];
  h[2] = (_Float16)lo[2]; h[3] = (_Float16)lo[3];
  h[4] = (_Float16)hi[0]; h[5] = (_Float16)hi[1];
  h[6] = (_Float16)hi[2]; h[7] = (_Float16)hi[3];
  return h;
}

// ---------------- prep: masked f16 weights in K=32 MFMA-A fragment order ----
// Fragment (frag, lane) holds A[m][k]: m = jt*16 + (lane&15),
// k = kt*32 + (e>>2)*16 + (lane>>4)*4 + (e&3)  (e=0..7, two stacked K=16
// halves). Stored at wf[frag*512 + lane*8 + e].
__global__ void prep_weights(const float* __restrict__ W1, const float* __restrict__ Wc,
                             const float* __restrict__ W2, const float* __restrict__ W3,
                             _Float16* __restrict__ wf) {
  int tid = blockIdx.x * blockDim.x + threadIdx.x;
  if (tid >= N_FRAGS * 64) return;
  int frag = tid >> 6;
  int lane = tid & 63;
  int q = lane >> 4, c = lane & 15;
  int L, jt, kt;
  if (frag < L2_BASE)      { L = 0; jt = frag / 3;              kt = frag % 3; }
  else if (frag < L3_BASE) { L = 1; jt = (frag - L2_BASE) >> 2; kt = (frag - L2_BASE) & 3; }
  else                     { L = 2; jt = (frag - L3_BASE) >> 2; kt = (frag - L3_BASE) & 3; }
  int j = jt * 16 + c;  // output unit (row of W)
  half8 v;
#pragma unroll
  for (int e = 0; e < 8; ++e) {
    int k = kt * 32 + (e >> 2) * 16 + q * 4 + (e & 3);
    float w;
    if (L == 0) {
      // layer1 K-dim is [x(32) | cond(64)]; mask m1 = (j%31 >= k), Wc unmasked
      if (k < NI) w = ((j % 31) >= k) ? W1[j * NI + k] : 0.f;
      else        w = Wc[j * NC + (k - NI)];
    } else if (L == 1) {
      w = ((j % 31) >= (k % 31)) ? W2[j * HD + k] : 0.f;          // m2
    } else {
      w = (((j % 32) - 1) >= (k % 31)) ? W3[j * HD + k] : 0.f;    // m3
    }
    v[e] = (_Float16)w;
  }
  *(half8*)(wf + (size_t)tid * 8) = v;
}

// ---------------- fused main kernel ----------------
// 8 waves/block, each wave owns 32 batch rows (nt = 2 tiles of 16).
// Grid = B/(8*32) = 2048 blocks.
__global__ __launch_bounds__(512, 4) void made_fused(
    const float* __restrict__ x, const float* __restrict__ cond,
    const float* __restrict__ b1, const float* __restrict__ b2,
    const float* __restrict__ b3, const _Float16* __restrict__ wf,
    float* __restrict__ out) {
  // L2+L3 weight fragments staged in LDS: frags 24..71 -> 48 * 1KB = 48KB
  __shared__ __align__(16) _Float16 wlds[48 * 512];

  const int tid  = threadIdx.x;
  const int lane = tid & 63;
  const int wid  = tid >> 6;
  const int q = lane >> 4, c = lane & 15;
  const long rowbase = ((long)blockIdx.x * 8 + wid) * 32;

  // ---- async-stage L2/L3 weights into LDS (48KB, 6KB per wave, 16B/lane) ---
  // global_load_lds: LDS dest = wave-uniform base + lane*16 (linear), matches
  // the linear fragment layout. Drained by the __syncthreads() after L1.
  {
    const char* gsrc = (const char*)(wf + L2_BASE * 512) + wid * 6144;
    char* lbase = (char*)wlds + wid * 6144;
#pragma unroll
    for (int i = 0; i < 6; ++i) {
      __builtin_amdgcn_global_load_lds(
          (const __attribute__((address_space(1))) void*)(gsrc + i * 1024 + lane * 16),
          (__attribute__((address_space(3))) void*)(lbase + i * 1024),
          16, 0, 0);
    }
  }

  // ---- L1 B-fragments (activations^T): bf[kt][nt], kt over [x|cond] K=96
  half8 bf[3][2];
#pragma unroll
  for (int nt = 0; nt < 2; ++nt) {
    const float* xr = x    + (rowbase + nt * 16 + c) * NI;
    const float* cr = cond + (rowbase + nt * 16 + c) * NC;
    bf[0][nt] = cvt8(*(const f32x4*)(xr + q * 4), *(const f32x4*)(xr + 16 + q * 4));
    bf[1][nt] = cvt8(*(const f32x4*)(cr + q * 4), *(const f32x4*)(cr + 16 + q * 4));
    bf[2][nt] = cvt8(*(const f32x4*)(cr + 32 + q * 4), *(const f32x4*)(cr + 48 + q * 4));
  }

  // ---- layer 1: D1[j][b] = W1c @ [x|cond]^T + b1, relu  (8 jt x 3 kt32)
  // weights from GLOBAL (L2-resident, overlaps x/cond HBM latency).
  // jt split in 2 halves of 4 -> acc file is 32 regs, reused across layers.
  f32x4 acc[4][2];
  half8 h1[4][2];
#pragma unroll
  for (int jh = 0; jh < 2; ++jh) {
#pragma unroll
    for (int j4 = 0; j4 < 4; ++j4) {
      f32x4 bv = *(const f32x4*)(b1 + (jh * 4 + j4) * 16 + q * 4);
      acc[j4][0] = bv; acc[j4][1] = bv;
    }
#pragma unroll
    for (int j4 = 0; j4 < 4; ++j4) {
      int jt = jh * 4 + j4;
#pragma unroll
      for (int kt = 0; kt < 3; ++kt) {
        half8 a = *(const half8*)(wf + (((jt * 3 + kt) * 64 + lane) << 3));
#pragma unroll
        for (int nt = 0; nt < 2; ++nt)
          acc[j4][nt] = __builtin_amdgcn_mfma_f32_16x16x32_f16(a, bf[kt][nt], acc[j4][nt], 0, 0, 0);
      }
    }
    // C/D tile pair (2p, 2p+1) == lower/upper K=16 halves of next-layer B frag
#pragma unroll
    for (int p = 0; p < 2; ++p)
#pragma unroll
      for (int nt = 0; nt < 2; ++nt)
        h1[jh * 2 + p][nt] = cvt8(relu4(acc[p * 2][nt]), relu4(acc[p * 2 + 1][nt]));
  }

  __syncthreads();  // LDS weights ready; all later weight reads hit LDS

  // ---- layer 2 (8 jt x 4 kt32), weights from LDS
  half8 h2[4][2];
#pragma unroll
  for (int jh = 0; jh < 2; ++jh) {
#pragma unroll
    for (int j4 = 0; j4 < 4; ++j4) {
      f32x4 bv = *(const f32x4*)(b2 + (jh * 4 + j4) * 16 + q * 4);
      acc[j4][0] = bv; acc[j4][1] = bv;
    }
#pragma unroll
    for (int j4 = 0; j4 < 4; ++j4) {
      int jt = jh * 4 + j4;
#pragma unroll
      for (int kt = 0; kt < 4; ++kt) {
        half8 a = *(const half8*)(wlds + (((jt * 4 + kt) * 64 + lane) << 3));
#pragma unroll
        for (int nt = 0; nt < 2; ++nt)
          acc[j4][nt] = __builtin_amdgcn_mfma_f32_16x16x32_f16(a, h1[kt][nt], acc[j4][nt], 0, 0, 0);
      }
    }
#pragma unroll
    for (int p = 0; p < 2; ++p)
#pragma unroll
      for (int nt = 0; nt < 2; ++nt)
        h2[jh * 2 + p][nt] = cvt8(relu4(acc[p * 2][nt]), relu4(acc[p * 2 + 1][nt]));
  }

  // ---- layer 3 (4 jt x 4 kt32), weights from LDS: o[0:32]=m_, o[32:64]=a
#pragma unroll
  for (int jt = 0; jt < 4; ++jt) {
    f32x4 bv = *(const f32x4*)(b3 + jt * 16 + q * 4);
    acc[jt][0] = bv; acc[jt][1] = bv;
  }
#pragma unroll
  for (int jt = 0; jt < 4; ++jt)
#pragma unroll
    for (int kt = 0; kt < 4; ++kt) {
      half8 a = *(const half8*)(wlds + (((32 + jt * 4 + kt) * 64 + lane) << 3));
#pragma unroll
      for (int nt = 0; nt < 2; ++nt)
        acc[jt][nt] = __builtin_amdgcn_mfma_f32_16x16x32_f16(a, h2[kt][nt], acc[jt][nt], 0, 0, 0);
    }

  // ---- epilogue: lane owns batch row m = rowbase+nt*16+c, output idx
  // i = q*4+r (jt0/jt2) and 16+q*4+r (jt1/jt3); m_ and a pair up in-lane.
#pragma unroll
  for (int nt = 0; nt < 2; ++nt) {
    long m = rowbase + nt * 16 + c;
    const float* xr = x + m * NI;   // L2-hit re-read (saves regs held live)
    f32x4 xa = *(const f32x4*)(xr + q * 4);
    f32x4 xb = *(const f32x4*)(xr + 16 + q * 4);
    f32x4 mva = acc[0][nt], mvb = acc[1][nt];
    f32x4 ava = acc[2][nt], avb = acc[3][nt];
    f32x4 ua, ub;
    float s = 0.f;
#pragma unroll
    for (int i = 0; i < 4; ++i) {
      float aa = fminf(fmaxf(ava[i], -5.f), 5.f);
      float ab = fminf(fmaxf(avb[i], -5.f), 5.f);
      ua[i] = (xa[i] - mva[i]) * __expf(-aa);
      ub[i] = (xb[i] - mvb[i]) * __expf(-ab);
      s += aa + ab;
    }
    *(f32x4*)(out + m * NI + q * 4) = ua;
    *(f32x4*)(out + m * NI + 16 + q * 4) = ub;
    s += __shfl_xor(s, 16);
    s += __shfl_xor(s, 32);
    if (q == 0) out[(long)B_ROWS * NI + m] = -s;  // logdet
  }
}

extern "C" void kernel_launch(void* const* d_in, const int* in_sizes, int n_in,
                              void* d_out, int out_size, void* d_ws, size_t ws_size,
                              hipStream_t stream) {
  const float* x    = (const float*)d_in[0];
  const float* cond = (const float*)d_in[1];
  const float* W1   = (const float*)d_in[2];
  const float* b1   = (const float*)d_in[3];
  const float* Wc   = (const float*)d_in[4];
  const float* W2   = (const float*)d_in[5];
  const float* b2   = (const float*)d_in[6];
  const float* W3   = (const float*)d_in[7];
  const float* b3   = (const float*)d_in[8];
  _Float16* wf = (_Float16*)d_ws;  // 72 frags * 512 halfs * 2B = 72 KB

  prep_weights<<<(N_FRAGS * 64 + 255) / 256, 256, 0, stream>>>(W1, Wc, W2, W3, wf);
  made_fused<<<B_ROWS / 256, 512, 0, stream>>>(x, cond, b1, b2, b3, wf, (float*)d_out);
}